// Round 8
// baseline (142.080 us; speedup 1.0000x reference)
//
#include <hip/hip_runtime.h>
#include <hip/hip_bf16.h>

#define BATCH 8
#define MAXPOS 2048
#define SEQ 2046
#define NH 12
#define HD 64
#define NCSLOT 254      // ci = c/16 in [-127,126], cslot = ci+127
#define TSTEPS 64       // K-chunks of 32 covering t=0..2047 (zero-padded past 2045)
#define PLANE (NH * HD) // 768

typedef __attribute__((ext_vector_type(4))) float floatx4;
typedef __attribute__((ext_vector_type(8))) short shortx8;

// ws layout: [Atile: 12*254*512 bf16 = 3,121,152 B][Vbf: 8*12*256*512 bf16 = 25,165,824 B]
#define ATILE_BYTES (NH * NCSLOT * 512 * 2)

#define GLOAD_LDS16(src, dst)                                                  \
    __builtin_amdgcn_global_load_lds(                                          \
        (const __attribute__((address_space(1))) void*)(src),                  \
        (__attribute__((address_space(3))) void*)(dst), 16, 0, 0)

#define NB_V2  (BATCH * TSTEPS)        // 512
#define NB_ZPB NH                      // 12
#define NB_A   (NCSLOT * NH)           // 3048

// ---------------------------------------------------------------------------
// prep_v (R8): SPLIT OUT as its own kernel (diagnostic: makes its duration
// visible in the top-5 counter table). Logic identical to R7's prep_V branch.
// ---------------------------------------------------------------------------
__global__ __launch_bounds__(256)
void prep_v(const float* __restrict__ v, ushort* __restrict__ vbf) {
    __shared__ __align__(16) ushort L[32][768];   // 48 KB
    const int bi  = blockIdx.x;
    const int tid = threadIdx.x;
    const int b  = bi >> 6;
    const int tc = bi & 63;
    const int t0 = tc * 32;
    const float* vb = v + (size_t)(b * MAXPOS + 1 + t0) * PLANE;
#pragma unroll
    for (int i = 0; i < 24; ++i) {
        const int f = i * 256 + tid;    // float4 index in [0,6144)
        const int r = f / 192;          // row 0..31
        const int s = f - r * 192;      // float4 within row
        float4 val = make_float4(0.f, 0.f, 0.f, 0.f);
        if (t0 + r < SEQ) val = *(const float4*)(vb + (size_t)f * 4);
        __hip_bfloat16 c0 = __float2bfloat16(val.x);
        __hip_bfloat16 c1 = __float2bfloat16(val.y);
        __hip_bfloat16 c2 = __float2bfloat16(val.z);
        __hip_bfloat16 c3 = __float2bfloat16(val.w);
        ushort4 pk;
        pk.x = *(ushort*)&c0; pk.y = *(ushort*)&c1;
        pk.z = *(ushort*)&c2; pk.w = *(ushort*)&c3;
        *(ushort4*)&L[r][(s * 4) ^ ((r >> 3) * 16)] = pk;
    }
    __syncthreads();
    const int wv   = tid >> 6;
    const int lane = tid & 63;
    const int q    = lane >> 4;
    const int dcol = lane & 15;
    const int cb   = wv * 16 + dcol;
#pragma unroll
    for (int h = 0; h < NH; ++h) {
        const int pc = (h * 64 + cb) ^ (q * 16);
        ushort pk[8];
#pragma unroll
        for (int j = 0; j < 8; ++j) pk[j] = L[q * 8 + j][pc];
        *(uint4*)(vbf + ((size_t)((b * NH + h) * TSTEPS + tc) * 4 + wv) * 512 + lane * 8) = *(uint4*)pk;
    }
}

// ---------------------------------------------------------------------------
// prep_rest (R8): zpb + prep_A + zeros. Split from prep_V so prep_A blocks
// get back their small-LDS occupancy (R7's 48 KB union capped them at 3/CU).
// ---------------------------------------------------------------------------
__global__ __launch_bounds__(256)
void prep_rest(const float* __restrict__ w, const float* __restrict__ off,
               ushort* __restrict__ atile, float* __restrict__ out) {
    const int bi  = blockIdx.x;
    const int tid = threadIdx.x;

    if (bi < NB_ZPB) {
        // ---- zpb scan
        __shared__ float Es[SEQ];
        __shared__ float Ss[SEQ];
        __shared__ float wsum[4];
        const int h    = bi;
        const int wid  = tid >> 6;
        const int lane = tid & 63;
        const float offh = off[h];
        const float* wh  = w + h * SEQ;
        for (int i = tid; i < SEQ; i += 256) Es[i] = __expf(wh[i] - offh);
        __syncthreads();
        const int base = tid * 8;
        float loc[8];
        float s = 0.f;
#pragma unroll
        for (int j = 0; j < 8; ++j) {
            float e = (base + j < SEQ) ? Es[base + j] : 0.f;
            s += e; loc[j] = s;
        }
        float sc = s;
#pragma unroll
        for (int d = 1; d < 64; d <<= 1) {
            float t = __shfl_up(sc, d);
            if (lane >= d) sc += t;
        }
        if (lane == 63) wsum[wid] = sc;
        __syncthreads();
        float woff = 0.f;
        for (int k = 0; k < wid; ++k) woff += wsum[k];
        float prefix = woff + sc - s;
#pragma unroll
        for (int j = 0; j < 8; ++j)
            if (base + j < SEQ) Ss[base + j] = prefix + loc[j];
        __syncthreads();
        const float E0 = Es[0];
        const size_t zb = (size_t)BATCH * MAXPOS * PLANE;
        for (int i = tid; i < SEQ; i += 256)
            out[zb + (size_t)(i + 1) * NH + h] = Ss[i] + Ss[SEQ - 1 - i] - E0;
    } else if (bi < NB_ZPB + NB_A) {
        // ---- prep_A
        const int idx   = bi - NB_ZPB;
        const int cslot = idx % NCSLOT;
        const int h     = idx / NCSLOT;
        const float offh = off[h];
        const float* wh  = w + h * SEQ;
        const int ci   = cslot - 127;
        const int lane = tid >> 2;
        const int jp   = (tid & 3) * 2;
        const int q    = lane >> 4;
        const int m    = lane & 15;
        const int d0   = 16 * ci + q * 8 - m + jp;
        ushort pk[2];
#pragma unroll
        for (int e = 0; e < 2; ++e) {
            int k = d0 + e; k = (k < 0) ? -k : k;
            float val = (k < SEQ) ? __expf(wh[k] - offh) : 0.f;
            __hip_bfloat16 bv = __float2bfloat16(val);
            pk[e] = *(ushort*)&bv;
        }
        *(ushort2*)(atile + ((size_t)(h * NCSLOT + cslot) * 512 + lane * 8 + jp)) = *(ushort2*)pk;
    } else {
        // ---- zero boundary positions (p=0, p=2047) of both outputs
        const int i = (bi - NB_ZPB - NB_A) * 256 + tid;
        if (i < 2 * BATCH * PLANE) {
            int side = i / (BATCH * PLANE);
            int r    = i % (BATCH * PLANE);
            int b    = r / PLANE;
            int j    = r % PLANE;
            int p    = side ? (MAXPOS - 1) : 0;
            out[((size_t)b * MAXPOS + p) * PLANE + j] = 0.f;
        }
        if (i < 2 * NH) {
            size_t zb = (size_t)BATCH * MAXPOS * PLANE;
            int p = (i < NH) ? 0 : (MAXPOS - 1);
            out[zb + (size_t)p * NH + (i % NH)] = 0.f;
        }
    }
}

// ---------------------------------------------------------------------------
// gemm_pbv (R8): EARLY OPERAND READS — LDS reads overlap MFMA.
//   R6's residual (MfmaUtil 46%) is barrier-phase alignment: all 12 waves
//   burst their 6 ds_read_b128 right after the barrier while the MFMA pipe
//   idles. Fix: ping-pong operand banks in registers; during step tc, read
//   chunk tc+1's operands BETWEEN the two 8-MFMA halves so the LDS pipe and
//   MFMA pipe run concurrently. Per step:
//     {stage(tc+3); setprio; 8 MFMA (s2,s3 on OLD A bank x B(tc));
//      s_waitcnt vmcnt(2/1); early ds_read: A(tc+1) s0,s1 -> old-A bank,
//      B(tc+1) -> alt B bank; sched_barrier(0); setprio; 8 MFMA (s0,s1 on
//      NEW A bank x B(tc)); s_barrier}
//   Correctness protocol: stage DISTANCE 3 (stage(tc) covers chunk tc+3) so
//   a stage batch is drained by every wave's leave-current wait at step
//   tc+2, hence cross-wave visible at barrier(tc+2) = one barrier BEFORE
//   the early-read of chunk tc+3 at step tc+2... i.e. batch b (chunk b+3)
//   drains at wait(b+1) [leave-current vmcnt(2)/(1) drains batches <= b],
//   visible at barrier(b+1), early-read at step b+2 > barrier(b+1). OK.
//   WAR ring-4 B: stage(tc) writes slot (tc+3)&3 = (tc-1)&3, whose last
//   touch was the early-read at step tc-2 (pre-barrier(tc-2)) -> 2 barriers
//   slack. A ring-32: ample. Toeplitz rotation preserved: s2,s3 of tc+1 =
//   s0,s1 of tc (already in regs).
//   LDS unchanged 48 KB (A ring-32 + B ring-4), 3 blocks/CU, XCD swizzle.
// ---------------------------------------------------------------------------

#define WAITC                                                                  \
  do {                                                                         \
    if (wvu < 2) asm volatile("s_waitcnt vmcnt(2)" ::: "memory");              \
    else         asm volatile("s_waitcnt vmcnt(1)" ::: "memory");              \
  } while (0)
#define WAIT0 asm volatile("s_waitcnt vmcnt(0)" ::: "memory")
#define BARRIER asm volatile("s_barrier" ::: "memory")

// One K-step tc (T4 = tc&3, E = offset in 4-step window).
// AO0/1: old A bank (holds s2,s3 of tc; overwritten by early-read of tc+1's
// s0,s1). AN0/1: new A bank (s0,s1 of tc). BC: B(tc) regs. BN: bank that
// receives B(tc+1). STG: stage chunk tc+3. W0: use vmcnt(0). ER: early-read.
#define STEP(T4, E, AO0, AO1, AN0, AN1, BC, BN, STG, W0, ER)                   \
  do {                                                                         \
    if (STG) {                                                                 \
        if (wvu < 2)                                                           \
            GLOAD_LDS16(aSt + (E) * 1024, &As[(csw + 2 * (E)) & 31][0]);       \
        GLOAD_LDS16(bSt + (E) * 2048, &Bs[((T4) + 3) & 3][wvu][0]);            \
    }                                                                          \
    __builtin_amdgcn_s_setprio(1);                                             \
    _Pragma("unroll")                                                          \
    for (int dt = 0; dt < 4; ++dt)                                             \
        acc[2][dt] = __builtin_amdgcn_mfma_f32_16x16x32_bf16(AO0, BC[dt], acc[2][dt], 0, 0, 0); \
    _Pragma("unroll")                                                          \
    for (int dt = 0; dt < 4; ++dt)                                             \
        acc[3][dt] = __builtin_amdgcn_mfma_f32_16x16x32_bf16(AO1, BC[dt], acc[3][dt], 0, 0, 0); \
    __builtin_amdgcn_s_setprio(0);                                             \
    if (W0) { WAIT0; } else { WAITC; }                                         \
    if (ER) {                                                                  \
        AO0 = *(const shortx8*)(&As[(ab + 2 * (E) + 2) & 31][lane8]);          \
        AO1 = *(const shortx8*)(&As[(ab + 2 * (E) + 1) & 31][lane8]);          \
        _Pragma("unroll")                                                      \
        for (int dt = 0; dt < 4; ++dt)                                         \
            BN[dt] = *(const shortx8*)(&Bs[((T4) + 1) & 3][dt][lane8]);        \
        __builtin_amdgcn_sched_barrier(0);                                     \
    }                                                                          \
    __builtin_amdgcn_s_setprio(1);                                             \
    _Pragma("unroll")                                                          \
    for (int dt = 0; dt < 4; ++dt)                                             \
        acc[0][dt] = __builtin_amdgcn_mfma_f32_16x16x32_bf16(AN0, BC[dt], acc[0][dt], 0, 0, 0); \
    _Pragma("unroll")                                                          \
    for (int dt = 0; dt < 4; ++dt)                                             \
        acc[1][dt] = __builtin_amdgcn_mfma_f32_16x16x32_bf16(AN1, BC[dt], acc[1][dt], 0, 0, 0); \
    __builtin_amdgcn_s_setprio(0);                                             \
    BARRIER;                                                                   \
  } while (0)

__global__ __launch_bounds__(256, 3)
void gemm_pbv(const ushort* __restrict__ atile, const ushort* __restrict__ vbf,
              float* __restrict__ out) {
    __shared__ short As[32][512];    // 32 KB: A sliding window, ring-32 over cslot
    __shared__ short Bs[4][4][512];  // 16 KB: B ring-4

    const int bid  = blockIdx.x;               // 0..767
    const int l    = (bid & 7) * 96 + (bid >> 3);  // XCD-contiguous logical id
    const int g    = l >> 3;                   // (h,bb) group 0..95
    const int nt   = l & 7;                    // 256-row tile 0..7
    const int h    = g >> 3;                   // 0..11
    const int bb   = g & 7;                    // 0..7
    const int tid  = threadIdx.x;
    const int wvu  = __builtin_amdgcn_readfirstlane(tid >> 6);  // wave id (SGPR)
    const int lane = tid & 63;
    const int lane8 = lane * 8;
    const int nt16  = nt * 16;

    floatx4 acc[4][4];
#pragma unroll
    for (int s = 0; s < 4; ++s)
#pragma unroll
        for (int dt = 0; dt < 4; ++dt) acc[s][dt] = (floatx4){0.f, 0.f, 0.f, 0.f};

    const ushort* aBase  = atile + (size_t)h * NCSLOT * 512;
    const ushort* bPanel = vbf + (size_t)(bb * NH + h) * (TSTEPS * 4 * 512);

    // ---- prologue: A window for chunks 0..2 = cslots [112-nt16, 131-nt16]
    // (20 frags, 5/wave) + B chunks 0,1,2 (1 frag/wave each). Drain all.
    {
        const int cbase = 112 - nt16;   // >= 0 (nt<=7)
        for (int j = wvu * 5; j < wvu * 5 + 5; ++j) {
            const int cs = cbase + j;
            GLOAD_LDS16(aBase + (size_t)cs * 512 + lane8, &As[cs & 31][0]);
        }
        GLOAD_LDS16(bPanel + (0 * 4 + wvu) * 512 + lane8, &Bs[0][wvu][0]);
        GLOAD_LDS16(bPanel + (1 * 4 + wvu) * 512 + lane8, &Bs[1][wvu][0]);
        GLOAD_LDS16(bPanel + (2 * 4 + wvu) * 512 + lane8, &Bs[2][wvu][0]);
    }
    WAIT0; BARRIER;   // chunks 0..2 resident

    // A read mapping: frag s of chunk tc -> ring slot (ab + 2tc - s)&31,
    // ab = 127 - nt16 - 4*wvu. Stage cursors (distance 3, chunk tc+3):
    // wv<2 stages cslot csw + 2tc (csw = 133 - nt16 - wvu).
    int ab  = 127 - nt16 - 4 * wvu;
    int csw = 133 - nt16 - wvu;
    const ushort* aSt = aBase + (size_t)(133 - nt16 - wvu) * 512 + lane8;
    const ushort* bSt = bPanel + (3 * 4 + wvu) * 512 + lane8;

    // ---- pre-seed register banks for tc=0:
    // old bank (s2,s3 of chunk 0): slots ab-2, ab-3 ; new bank (s0,s1): ab, ab-1
    // B bank x: B(0).
    shortx8 ax0, ax1, ay0, ay1, bx[4], by[4];
    ax0 = *(const shortx8*)(&As[(ab - 2) & 31][lane8]);
    ax1 = *(const shortx8*)(&As[(ab - 3) & 31][lane8]);
    ay0 = *(const shortx8*)(&As[(ab) & 31][lane8]);
    ay1 = *(const shortx8*)(&As[(ab - 1) & 31][lane8]);
#pragma unroll
    for (int dt = 0; dt < 4; ++dt) bx[dt] = *(const shortx8*)(&Bs[0][dt][lane8]);

    // ---- main loop: tc = 0..59
    for (int u = 0; u < 15; ++u) {
        STEP(0, 0, ax0, ax1, ay0, ay1, bx, by, 1, 0, 1);
        STEP(1, 1, ay0, ay1, ax0, ax1, by, bx, 1, 0, 1);
        STEP(2, 2, ax0, ax1, ay0, ay1, bx, by, 1, 0, 1);
        STEP(3, 3, ay0, ay1, ax0, ax1, by, bx, 1, 0, 1);
        ab += 8; csw += 8; aSt += 4 * 1024; bSt += 4 * 2048;
    }
    // ---- tail: tc = 60..63
    STEP(0, 0, ax0, ax1, ay0, ay1, bx, by, 1, 0, 1);   // tc=60: stages chunk 63
    STEP(1, 1, ay0, ay1, ax0, ax1, by, bx, 0, 1, 1);   // tc=61: drain all
    STEP(2, 2, ax0, ax1, ay0, ay1, bx, by, 0, 1, 1);   // tc=62: early-read 63
    STEP(3, 3, ay0, ay1, ax0, ax1, by, bx, 0, 1, 0);   // tc=63: final compute

    // epilogue: D row=(lane>>4)*4+r (n-local), col=lane&15 (d-local)
    const int q    = lane >> 4;
    const int dcol = lane & 15;
    const int nB   = nt * 256 + wvu * 64;
#pragma unroll
    for (int s = 0; s < 4; ++s) {
        int nsb = nB + s * 16 + q * 4;
#pragma unroll
        for (int r = 0; r < 4; ++r) {
            int n = nsb + r;
            if (n < SEQ) {
                float* ob = out + ((size_t)(bb * MAXPOS + 1 + n) * NH + h) * HD + dcol;
#pragma unroll
                for (int dt = 0; dt < 4; ++dt) ob[dt * 16] = acc[s][dt][r];
            }
        }
    }
}

extern "C" void kernel_launch(void* const* d_in, const int* in_sizes, int n_in,
                              void* d_out, int out_size, void* d_ws, size_t ws_size,
                              hipStream_t stream) {
    const float* v   = (const float*)d_in[0];  // (8, 2048, 12, 64)
    const float* off = (const float*)d_in[1];  // (1, 12)
    const float* w   = (const float*)d_in[2];  // (1, 12, 2046)
    float* out = (float*)d_out;

    ushort* atile = (ushort*)d_ws;
    ushort* vbf   = (ushort*)((char*)d_ws + ATILE_BYTES);

    prep_v<<<NB_V2, 256, 0, stream>>>(v, vbf);
    prep_rest<<<NB_ZPB + NB_A + 48, 256, 0, stream>>>(w, off, atile, out);
    gemm_pbv<<<768, 256, 0, stream>>>(atile, vbf, out);
}

// Round 9
// 137.017 us; speedup vs baseline: 1.0370x; 1.0370x over previous
//
#include <hip/hip_runtime.h>
#include <hip/hip_bf16.h>

#define BATCH 8
#define MAXPOS 2048
#define SEQ 2046
#define NH 12
#define HD 64
#define NCSLOT 254      // ci = c/16 in [-127,126], cslot = ci+127
#define TSTEPS 64       // K-chunks of 32 covering t=0..2047 (zero-padded past 2045)
#define PLANE (NH * HD) // 768

typedef __attribute__((ext_vector_type(4))) float floatx4;
typedef __attribute__((ext_vector_type(8))) short shortx8;

// ws layout: [Atile: 12*254*512 bf16 = 3,121,152 B][Vbf: 8*12*256*512 bf16 = 25,165,824 B]
#define ATILE_BYTES (NH * NCSLOT * 512 * 2)

#define GLOAD_LDS16(src, dst)                                                  \
    __builtin_amdgcn_global_load_lds(                                          \
        (const __attribute__((address_space(1))) void*)(src),                  \
        (__attribute__((address_space(3))) void*)(dst), 16, 0, 0)

#define NB_V2  (BATCH * TSTEPS)        // 512
#define NB_ZPB NH                      // 12
#define NB_A   (NCSLOT * NH)           // 3048

// ---------------------------------------------------------------------------
// prep_all (R9 = R7's merged version, reverted from R8's split which cost
// ~5 us of stream serialization). Single launch; phases co-schedule.
// ---------------------------------------------------------------------------
__global__ __launch_bounds__(256)
void prep_all(const float* __restrict__ v, const float* __restrict__ w,
              const float* __restrict__ off, ushort* __restrict__ atile,
              ushort* __restrict__ vbf, float* __restrict__ out) {
    __shared__ __align__(16) char smem[32 * 768 * 2];   // 48 KB, union'd per phase
    const int bi  = blockIdx.x;
    const int tid = threadIdx.x;

    if (bi < NB_V2) {
        // ---- prep_V: block = (b,tc); contiguous 96 KB read, 12-head emit
        ushort (*L)[768] = (ushort(*)[768])smem;
        const int b  = bi >> 6;
        const int tc = bi & 63;
        const int t0 = tc * 32;
        const float* vb = v + (size_t)(b * MAXPOS + 1 + t0) * PLANE;
#pragma unroll
        for (int i = 0; i < 24; ++i) {
            const int f = i * 256 + tid;    // float4 index in [0,6144)
            const int r = f / 192;          // row 0..31
            const int s = f - r * 192;      // float4 within row
            float4 val = make_float4(0.f, 0.f, 0.f, 0.f);
            if (t0 + r < SEQ) val = *(const float4*)(vb + (size_t)f * 4);
            __hip_bfloat16 c0 = __float2bfloat16(val.x);
            __hip_bfloat16 c1 = __float2bfloat16(val.y);
            __hip_bfloat16 c2 = __float2bfloat16(val.z);
            __hip_bfloat16 c3 = __float2bfloat16(val.w);
            ushort4 pk;
            pk.x = *(ushort*)&c0; pk.y = *(ushort*)&c1;
            pk.z = *(ushort*)&c2; pk.w = *(ushort*)&c3;
            *(ushort4*)&L[r][(s * 4) ^ ((r >> 3) * 16)] = pk;
        }
        __syncthreads();
        const int wv   = tid >> 6;
        const int lane = tid & 63;
        const int q    = lane >> 4;
        const int dcol = lane & 15;
        const int cb   = wv * 16 + dcol;
#pragma unroll
        for (int h = 0; h < NH; ++h) {
            const int pc = (h * 64 + cb) ^ (q * 16);
            ushort pk[8];
#pragma unroll
            for (int j = 0; j < 8; ++j) pk[j] = L[q * 8 + j][pc];
            *(uint4*)(vbf + ((size_t)((b * NH + h) * TSTEPS + tc) * 4 + wv) * 512 + lane * 8) = *(uint4*)pk;
        }
    } else if (bi < NB_V2 + NB_ZPB) {
        // ---- zpb scan
        float* Es   = (float*)smem;          // SEQ floats
        float* Ss   = (float*)smem + 2048;   // SEQ floats
        float* wsum = (float*)smem + 4096;   // 4 floats
        const int h    = bi - NB_V2;
        const int wid  = tid >> 6;
        const int lane = tid & 63;
        const float offh = off[h];
        const float* wh  = w + h * SEQ;
        for (int i = tid; i < SEQ; i += 256) Es[i] = __expf(wh[i] - offh);
        __syncthreads();
        const int base = tid * 8;
        float loc[8];
        float s = 0.f;
#pragma unroll
        for (int j = 0; j < 8; ++j) {
            float e = (base + j < SEQ) ? Es[base + j] : 0.f;
            s += e; loc[j] = s;
        }
        float sc = s;
#pragma unroll
        for (int d = 1; d < 64; d <<= 1) {
            float t = __shfl_up(sc, d);
            if (lane >= d) sc += t;
        }
        if (lane == 63) wsum[wid] = sc;
        __syncthreads();
        float woff = 0.f;
        for (int k = 0; k < wid; ++k) woff += wsum[k];
        float prefix = woff + sc - s;
#pragma unroll
        for (int j = 0; j < 8; ++j)
            if (base + j < SEQ) Ss[base + j] = prefix + loc[j];
        __syncthreads();
        const float E0 = Es[0];
        const size_t zb = (size_t)BATCH * MAXPOS * PLANE;
        for (int i = tid; i < SEQ; i += 256)
            out[zb + (size_t)(i + 1) * NH + h] = Ss[i] + Ss[SEQ - 1 - i] - E0;
    } else if (bi < NB_V2 + NB_ZPB + NB_A) {
        // ---- prep_A
        const int idx   = bi - NB_V2 - NB_ZPB;
        const int cslot = idx % NCSLOT;
        const int h     = idx / NCSLOT;
        const float offh = off[h];
        const float* wh  = w + h * SEQ;
        const int ci   = cslot - 127;
        const int lane = tid >> 2;
        const int jp   = (tid & 3) * 2;
        const int q    = lane >> 4;
        const int m    = lane & 15;
        const int d0   = 16 * ci + q * 8 - m + jp;
        ushort pk[2];
#pragma unroll
        for (int e = 0; e < 2; ++e) {
            int k = d0 + e; k = (k < 0) ? -k : k;
            float val = (k < SEQ) ? __expf(wh[k] - offh) : 0.f;
            __hip_bfloat16 bv = __float2bfloat16(val);
            pk[e] = *(ushort*)&bv;
        }
        *(ushort2*)(atile + ((size_t)(h * NCSLOT + cslot) * 512 + lane * 8 + jp)) = *(ushort2*)pk;
    } else {
        // ---- zero boundary positions (p=0, p=2047) of both outputs
        const int i = (bi - NB_V2 - NB_ZPB - NB_A) * 256 + tid;
        if (i < 2 * BATCH * PLANE) {
            int side = i / (BATCH * PLANE);
            int r    = i % (BATCH * PLANE);
            int b    = r / PLANE;
            int j    = r % PLANE;
            int p    = side ? (MAXPOS - 1) : 0;
            out[((size_t)b * MAXPOS + p) * PLANE + j] = 0.f;
        }
        if (i < 2 * NH) {
            size_t zb = (size_t)BATCH * MAXPOS * PLANE;
            int p = (i < NH) ? 0 : (MAXPOS - 1);
            out[zb + (size_t)p * NH + (i % NH)] = 0.f;
        }
    }
}

// ---------------------------------------------------------------------------
// gemm_pbv (R9): R6 protocol + NEW WAVE GEOMETRY 128n x 32d.
//   Block still 256n x 64d x 1bb, 4 waves: wn=wv>>1 owns 128 rows (8
//   16-row subtiles), wd=wv&1 owns 32 cols (2 16-col subtiles).
//   B reads per wave per step: 4 -> 2 (only the wd-half); A rotation
//   extends to 8 registers (a[s] at chunk tc = cslot 127-nt16-8wn+2tc-s;
//   step+1 shifts by 2 -> rotate a2..a7 <- a0..a5, read 2 new). Per-wave
//   LDS reads 6 -> 4 b128/step (block-wide 24 -> 16 KB/step, -33%).
//   Read-slot union over waves = [112,127]-nt16+2tc, IDENTICAL to R6 ->
//   staging (wv0,1 stage cslots 131/130-nt16+2tc), prologue window
//   [112,131]-nt16, B ring-4 distance-2, leave-current vmcnt(2)/(1) +
//   s_barrier per step: all bit-identical to R6's proven protocol.
//   MFMA order: s=2..7 (reg-resident) before s=0,1 (fresh reads).
// ---------------------------------------------------------------------------

#define WBAR                                                                   \
  do {                                                                         \
    if (wvu < 2) asm volatile("s_waitcnt vmcnt(2)\n\ts_barrier" ::: "memory"); \
    else         asm volatile("s_waitcnt vmcnt(1)\n\ts_barrier" ::: "memory"); \
  } while (0)
#define WBAR0 asm volatile("s_waitcnt vmcnt(0)\n\ts_barrier" ::: "memory")

#define MFMA_S(S, A)                                                           \
    acc[S][0] = __builtin_amdgcn_mfma_f32_16x16x32_bf16(A, bf0, acc[S][0], 0, 0, 0); \
    acc[S][1] = __builtin_amdgcn_mfma_f32_16x16x32_bf16(A, bf1, acc[S][1], 0, 0, 0);

// One K-step tc (T4 = tc&3 static, E = step offset in 4-step window).
// Rotate 8 A regs by 2, read 2 new A frags + 2 B frags (wd-half), stage
// (if STG) A cslot csw+2E (wv<2) and B frag wvu of chunk tc+2, then 16 MFMA.
#define STEP(T4, E, STG)                                                       \
  do {                                                                         \
    const int abE = ab + 2 * (E);                                              \
    shortx8 bf0, bf1;                                                          \
    a7 = a5; a6 = a4; a5 = a3; a4 = a2; a3 = a1; a2 = a0;                      \
    a0 = *(const shortx8*)(&As[(abE) & 31][lane8]);                            \
    a1 = *(const shortx8*)(&As[(abE - 1) & 31][lane8]);                        \
    bf0 = *(const shortx8*)(&Bs[T4][wd2][lane8]);                              \
    bf1 = *(const shortx8*)(&Bs[T4][wd2 + 1][lane8]);                          \
    if (STG) {                                                                 \
        if (wvu < 2)                                                           \
            GLOAD_LDS16(aSt + (E) * 1024, &As[(csw + 2 * (E)) & 31][0]);       \
        GLOAD_LDS16(bSt + (E) * 2048, &Bs[((T4) + 2) & 3][wvu][0]);            \
    }                                                                          \
    __builtin_amdgcn_s_setprio(1);                                             \
    MFMA_S(2, a2) MFMA_S(3, a3) MFMA_S(4, a4) MFMA_S(5, a5)                    \
    MFMA_S(6, a6) MFMA_S(7, a7) MFMA_S(0, a0) MFMA_S(1, a1)                    \
    __builtin_amdgcn_s_setprio(0);                                             \
  } while (0)

__global__ __launch_bounds__(256, 3)
void gemm_pbv(const ushort* __restrict__ atile, const ushort* __restrict__ vbf,
              float* __restrict__ out) {
    __shared__ short As[32][512];    // 32 KB: A sliding window, ring-32 over cslot
    __shared__ short Bs[4][4][512];  // 16 KB: B ring-4 (4 frags/chunk)

    const int bid  = blockIdx.x;               // 0..767
    const int l    = (bid & 7) * 96 + (bid >> 3);  // XCD-contiguous logical id
    const int g    = l >> 3;                   // (h,bb) group 0..95
    const int nt   = l & 7;                    // 256-row tile 0..7
    const int h    = g >> 3;                   // 0..11
    const int bb   = g & 7;                    // 0..7
    const int tid  = threadIdx.x;
    const int wvu  = __builtin_amdgcn_readfirstlane(tid >> 6);  // wave id (SGPR)
    const int lane = tid & 63;
    const int lane8 = lane * 8;
    const int nt16  = nt * 16;
    const int wn    = wvu >> 1;                // row-half: 128 rows
    const int wd2   = (wvu & 1) * 2;           // col-half: B frags wd2, wd2+1

    floatx4 acc[8][2];
#pragma unroll
    for (int s = 0; s < 8; ++s)
#pragma unroll
        for (int dt = 0; dt < 2; ++dt) acc[s][dt] = (floatx4){0.f, 0.f, 0.f, 0.f};

    const ushort* aBase  = atile + (size_t)h * NCSLOT * 512;
    const ushort* bPanel = vbf + (size_t)(bb * NH + h) * (TSTEPS * 4 * 512);

    // ---- prologue: A window cslots [112-nt16, 131-nt16] (20 frags, 5/wave)
    // + B chunks 0,1 (1 frag/wave each). Drain all.
    {
        const int cbase = 112 - nt16;   // >= 0 (nt<=7)
        for (int j = wvu * 5; j < wvu * 5 + 5; ++j) {
            const int cs = cbase + j;
            GLOAD_LDS16(aBase + (size_t)cs * 512 + lane8, &As[cs & 31][0]);
        }
        GLOAD_LDS16(bPanel + (0 * 4 + wvu) * 512 + lane8, &Bs[0][wvu][0]);
        GLOAD_LDS16(bPanel + (1 * 4 + wvu) * 512 + lane8, &Bs[1][wvu][0]);
    }
    WBAR0;   // chunks 0,1 resident

    // A read mapping: frag s of chunk tc -> ring slot (ab + 2tc - s)&31,
    // ab = 127 - nt16 - 8*wn. Stage cursors (distance 2, chunk tc+2):
    // wvu<2 stages cslot csw + 2tc (csw = 131 - nt16 - wvu).
    int ab  = 127 - nt16 - 8 * wn;
    int csw = 131 - nt16 - wvu;
    const ushort* aSt = aBase + (size_t)(131 - nt16 - wvu) * 512 + lane8;
    const ushort* bSt = bPanel + (2 * 4 + wvu) * 512 + lane8;

    // rotation pre-seed: pre-rotation a0..a5 = slots ab-2-s (s=0..5), so the
    // first STEP's rotate yields a2..a7 = chunk-0 frags s=2..7.
    shortx8 a0, a1, a2, a3, a4, a5, a6, a7;
    a0 = *(const shortx8*)(&As[(ab - 2) & 31][lane8]);
    a1 = *(const shortx8*)(&As[(ab - 3) & 31][lane8]);
    a2 = *(const shortx8*)(&As[(ab - 4) & 31][lane8]);
    a3 = *(const shortx8*)(&As[(ab - 5) & 31][lane8]);
    a4 = *(const shortx8*)(&As[(ab - 6) & 31][lane8]);
    a5 = *(const shortx8*)(&As[(ab - 7) & 31][lane8]);
    a6 = a0; a7 = a0;  // dead until overwritten; init to silence undef

    // ---- main loop: tc = 0..59 (15 x 4 steps), staging chunk tc+2
    for (int u = 0; u < 15; ++u) {
        STEP(0, 0, 1); WBAR;
        STEP(1, 1, 1); WBAR;
        STEP(2, 2, 1); WBAR;
        STEP(3, 3, 1); WBAR;
        ab += 8; csw += 8; aSt += 4 * 1024; bSt += 4 * 2048;
    }
    // ---- tail: tc = 60..63
    STEP(0, 0, 1); WBAR;    // tc=60: stages chunk 62
    STEP(1, 1, 1); WBAR;    // tc=61: stages chunk 63
    STEP(2, 2, 0); WBAR0;   // tc=62: drain chunk 63
    STEP(3, 3, 0);          // tc=63: final compute

    // epilogue: D row=(lane>>4)*4+r (n-local), col=lane&15 (d-local)
    const int q    = lane >> 4;
    const int dcol = lane & 15;
    const int nB   = nt * 256 + wn * 128;
    const int cB   = wd2 * 16 + dcol;      // wd*32 + dcol
#pragma unroll
    for (int s = 0; s < 8; ++s) {
        int nsb = nB + s * 16 + q * 4;
#pragma unroll
        for (int r = 0; r < 4; ++r) {
            int n = nsb + r;
            if (n < SEQ) {
                float* ob = out + ((size_t)(bb * MAXPOS + 1 + n) * NH + h) * HD + cB;
#pragma unroll
                for (int dt = 0; dt < 2; ++dt) ob[dt * 16] = acc[s][dt][r];
            }
        }
    }
}

extern "C" void kernel_launch(void* const* d_in, const int* in_sizes, int n_in,
                              void* d_out, int out_size, void* d_ws, size_t ws_size,
                              hipStream_t stream) {
    const float* v   = (const float*)d_in[0];  // (8, 2048, 12, 64)
    const float* off = (const float*)d_in[1];  // (1, 12)
    const float* w   = (const float*)d_in[2];  // (1, 12, 2046)
    float* out = (float*)d_out;

    ushort* atile = (ushort*)d_ws;
    ushort* vbf   = (ushort*)((char*)d_ws + ATILE_BYTES);

    prep_all<<<NB_V2 + NB_ZPB + NB_A + 48, 256, 0, stream>>>(v, w, off, atile, vbf, out);
    gemm_pbv<<<768, 256, 0, stream>>>(atile, vbf, out);
}